// Round 11
// baseline (845.540 us; speedup 1.0000x reference)
//
#include <hip/hip_runtime.h>
#include <hip/hip_bf16.h>
#include <math.h>

#define NB 8
#define NIN 3136
#define NOUT 784
#define DIN 96
#define DOUT 192
#define HID 384
#define TOK_IN (NB*NIN)    // 25088
#define TOK_OUT (NB*NOUT)  // 6272

// ---------------- window helper
__device__ __forceinline__ void window9(int n, int* ms, bool* dup) {
  int r = n / 56, c = n % 56;
  int rb = r >> 1, cb = c >> 1;
  #pragma unroll
  for (int j = 0; j < 9; j++) {
    int ro = rb + (j/3) - 1; ro = ro < 0 ? 0 : (ro > 27 ? 27 : ro);
    int co = cb + (j%3) - 1; co = co < 0 ? 0 : (co > 27 ? 27 : co);
    ms[j] = ro*28 + co;
  }
  #pragma unroll
  for (int j = 0; j < 9; j++) {
    bool d = false;
    #pragma unroll
    for (int i = 0; i < j; i++) d = d || (ms[i] == ms[j]);
    dup[j] = d;
  }
}

// ---------------- weight transposes + bias9 table (once per launch)
__global__ void k_tr(const float* __restrict__ cw, const float* __restrict__ kw,
                     const float* __restrict__ vw, const float* __restrict__ qw,
                     const float* __restrict__ w1, const float* __restrict__ w2,
                     const float* __restrict__ rpb, const int* __restrict__ qidx,
                     float* __restrict__ wct, float* __restrict__ wkv4, float* __restrict__ qw4,
                     float* __restrict__ w1_4, float* __restrict__ w2_4,
                     float* __restrict__ bias9) {
  int i = blockIdx.x * 256 + threadIdx.x;
  if (i < 165888) {
    int q = i & 3; int t1 = i >> 2;
    int co = t1 % 192; int t2 = t1 / 192;
    int kwi = t2 % 3; int t3 = t2 / 3;
    int ci4m = t3 % 6; int t4 = t3 / 6;
    int kh = t4 % 3; int ch = t4 / 3;      // ch in [0,4)
    wct[i] = cw[((co*96 + ch*24 + ci4m*4 + q)*3 + kh)*3 + kwi];
  } else if (i < 165888 + 27648) {
    int j = i - 165888; int q = j & 3; int rest = j >> 2;
    int o = rest % 288; int e = (rest / 288)*4 + q;
    wkv4[j] = (o < 96) ? kw[o*96 + e] : vw[(o-96)*96 + e];
  } else if (i < 165888 + 27648 + 18432) {
    int j = i - 165888 - 27648; int q = j & 3; int rest = j >> 2;
    int o = rest % 96; int e = (rest / 96)*4 + q;
    qw4[j] = qw[o*192 + e];
  } else if (i < 165888 + 27648 + 18432 + 73728) {
    int j = i - 165888 - 27648 - 18432; int q = j & 3; int rest = j >> 2;
    int hh = rest % 384; int e = (rest / 384)*4 + q;
    w1_4[j] = w1[hh*192 + e];
  } else if (i < 165888 + 27648 + 18432 + 73728 + 73728) {
    int j = i - 165888 - 27648 - 18432 - 73728; int q = j & 3; int rest = j >> 2;
    int o = rest % 192; int h = (rest / 192)*4 + q;
    w2_4[j] = w2[o*384 + h];
  } else if (i < 165888 + 27648 + 18432 + 73728 + 73728 + 28224) {
    int j = i - 165888 - 27648 - 18432 - 73728 - 73728;
    int j9 = j % 9; int n = j / 9;
    int ms[9]; bool dup[9];
    window9(n, ms, dup);
    bias9[j] = rpb[qidx[(size_t)n*NOUT + ms[j9]]];
  }
}

// ---------------- strided 3x3 conv seed, 4-way ci-split partial sums.
__global__ __launch_bounds__(224, 4) void k_conv(const float* __restrict__ x,
                                                 const float* __restrict__ wct,
                                                 float* __restrict__ s0, float* __restrict__ s1,
                                                 float* __restrict__ s2, float* __restrict__ s3) {
  __shared__ float xs[3][58][24];   // 16.7 KB
  int ho = blockIdx.x;
  int half = blockIdx.y & 1, ch = blockIdx.y >> 1;   // ch in [0,4)
  int b = blockIdx.z;
  int t = threadIdx.x;
  const float* xb0 = x + (size_t)b*NIN*DIN + ch*24;
  for (int i = t; i < 3*58*6; i += 224) {
    int q = i % 6; int rest = i / 6;
    int col = rest % 58; int kh = rest / 58;
    int h = 2*ho - 1 + kh, c = col - 1;
    float4 v = make_float4(0.f,0.f,0.f,0.f);
    if (h >= 0 && h < 56 && c >= 0 && c < 56)
      v = *(const float4*)(xb0 + ((size_t)h*56 + c)*DIN + q*4);
    *(float4*)&xs[kh][col][q*4] = v;
  }
  __syncthreads();
  int ol = t & 31, tg = t >> 5;       // tg in [0,7): wo = 4tg..4tg+3
  int co = half*96 + ol;
  float acc[4][3];
  #pragma unroll
  for (int i = 0; i < 4; i++) { acc[i][0]=0.f; acc[i][1]=0.f; acc[i][2]=0.f; }
  #pragma unroll
  for (int kh = 0; kh < 3; kh++) {
    const float4* wp = (const float4*)wct + (size_t)(ch*3 + kh)*3456 + co;
    const float* xb = &xs[kh][8*tg][0];
    #pragma unroll
    for (int ci4 = 0; ci4 < 6; ci4++) {
      float4 xr[9];
      #pragma unroll
      for (int c = 0; c < 9; c++) xr[c] = *(const float4*)(xb + c*24);
      #pragma unroll
      for (int kwv = 0; kwv < 3; kwv++) {
        float4 w0 = wp[kwv*192], w1 = wp[kwv*192 + 32], w2 = wp[kwv*192 + 64];
        #pragma unroll
        for (int i = 0; i < 4; i++) {
          float4 xv = xr[2*i + kwv];
          acc[i][0] += xv.x*w0.x + xv.y*w0.y + xv.z*w0.z + xv.w*w0.w;
          acc[i][1] += xv.x*w1.x + xv.y*w1.y + xv.z*w1.z + xv.w*w1.w;
          acc[i][2] += xv.x*w2.x + xv.y*w2.y + xv.z*w2.z + xv.w*w2.w;
        }
      }
      wp += 576; xb += 4;
    }
  }
  float* sp = (ch == 0) ? s0 : (ch == 1) ? s1 : (ch == 2) ? s2 : s3;
  #pragma unroll
  for (int i = 0; i < 4; i++)
    #pragma unroll
    for (int j = 0; j < 3; j++)
      sp[((size_t)b*NOUT + ho*28 + 4*tg + i)*DOUT + co + 32*j] = acc[i][j];
}

// ---------------- seed-sum(4) + LN -> xo, + LN + q-GEMM -> qb. 16 tok/block, 256 thr
__global__ __launch_bounds__(256) void k_lnq(const float* __restrict__ s0, const float* __restrict__ s1,
                                             const float* __restrict__ s2, const float* __restrict__ s3,
                                             const float* __restrict__ qw4,
                                             const float* __restrict__ lng, const float* __restrict__ lnb,
                                             float* __restrict__ xo, float* __restrict__ qb) {
  __shared__ float xt[16][196];
  int tok0 = blockIdx.x * 16;
  int t = threadIdx.x;
  int tok16 = t >> 4, l16 = t & 15;
  size_t base = (size_t)(tok0 + tok16)*DOUT;
  float v[12], s = 0.f, sq = 0.f;
  #pragma unroll
  for (int j = 0; j < 12; j++) {
    int e = l16 + 16*j;
    float vv = s0[base + e] + s1[base + e] + s2[base + e] + s3[base + e];
    v[j] = vv; s += vv; sq += vv*vv;
  }
  #pragma unroll
  for (int off = 8; off; off >>= 1) { s += __shfl_xor(s, off, 16); sq += __shfl_xor(sq, off, 16); }
  float mu = s * (1.f/192.f);
  float var = sq * (1.f/192.f) - mu*mu;
  float rs = rsqrtf(var + 1e-5f);
  float s2a = 0.f, sq2 = 0.f;
  #pragma unroll
  for (int j = 0; j < 12; j++) {
    int e = l16 + 16*j;
    float y = (v[j]-mu)*rs*lng[e] + lnb[e];
    xo[base + e] = y;
    v[j] = y; s2a += y; sq2 += y*y;
  }
  #pragma unroll
  for (int off = 8; off; off >>= 1) { s2a += __shfl_xor(s2a, off, 16); sq2 += __shfl_xor(sq2, off, 16); }
  float mu2 = s2a * (1.f/192.f);
  float var2 = sq2 * (1.f/192.f) - mu2*mu2;
  float rs2 = rsqrtf(var2 + 1e-5f);
  #pragma unroll
  for (int j = 0; j < 12; j++) {
    int e = l16 + 16*j;
    xt[tok16][e] = (v[j]-mu2)*rs2*lng[e] + lnb[e];
  }
  __syncthreads();
  int ol = t & 31, tg = t >> 5;
  float acc[2][3];
  #pragma unroll
  for (int i = 0; i < 2; i++) { acc[i][0]=0.f; acc[i][1]=0.f; acc[i][2]=0.f; }
  const float4* wp = (const float4*)qw4 + ol;
  for (int e4 = 0; e4 < 48; e4++) {
    float4 w0 = wp[0], w1 = wp[32], w2 = wp[64];
    #pragma unroll
    for (int i = 0; i < 2; i++) {
      float4 xv = *(const float4*)&xt[tg*2+i][e4*4];
      acc[i][0] += xv.x*w0.x + xv.y*w0.y + xv.z*w0.z + xv.w*w0.w;
      acc[i][1] += xv.x*w1.x + xv.y*w1.y + xv.z*w1.z + xv.w*w1.w;
      acc[i][2] += xv.x*w2.x + xv.y*w2.y + xv.z*w2.z + xv.w*w2.w;
    }
    wp += 96;
  }
  #pragma unroll
  for (int i = 0; i < 2; i++)
    #pragma unroll
    for (int j = 0; j < 3; j++)
      qb[(size_t)(tok0 + tg*2 + i)*DIN + ol + 32*j] = acc[i][j];
}

// ---------------- kv = LN(x) @ [k_w|v_w]^T, LN fused. 32 tokens/block, 256 thr, TM=4
__global__ __launch_bounds__(256) void k_kv(const float* __restrict__ x,
                                            const float* __restrict__ wkv4,
                                            const float* __restrict__ lng, const float* __restrict__ lnb,
                                            float* __restrict__ kvb) {
  __shared__ float xt[32][100];
  int tok0 = blockIdx.x * 32;
  int t = threadIdx.x;
  const float4* xp = (const float4*)(x + (size_t)tok0*DIN);
  for (int i = t; i < 32*24; i += 256) {
    int tok = i / 24, q = i % 24;
    *(float4*)&xt[tok][q*4] = xp[i];
  }
  __syncthreads();
  int tok8 = t >> 3, l8 = t & 7;
  float vv[12], s = 0.f, sq = 0.f;
  #pragma unroll
  for (int j = 0; j < 12; j++) {
    float v = xt[tok8][l8 + 8*j];
    vv[j] = v; s += v; sq += v*v;
  }
  #pragma unroll
  for (int off = 4; off; off >>= 1) { s += __shfl_xor(s, off, 8); sq += __shfl_xor(sq, off, 8); }
  float mu = s * (1.f/96.f);
  float var = sq * (1.f/96.f) - mu*mu;
  float rs = rsqrtf(var + 1e-5f);
  #pragma unroll
  for (int j = 0; j < 12; j++) {
    int e = l8 + 8*j;
    xt[tok8][e] = (vv[j]-mu)*rs*lng[e] + lnb[e];
  }
  __syncthreads();
  int ol = t & 31, tg = t >> 5;     // 8 groups x 4 tokens
  float acc[4][9];
  #pragma unroll
  for (int i = 0; i < 4; i++)
    #pragma unroll
    for (int j = 0; j < 9; j++) acc[i][j] = 0.f;
  const float4* wp = (const float4*)wkv4 + ol;
  for (int e4 = 0; e4 < 24; e4++) {
    float4 w[9];
    #pragma unroll
    for (int j = 0; j < 9; j++) w[j] = wp[32*j];
    #pragma unroll
    for (int i = 0; i < 4; i++) {
      float4 xv = *(const float4*)&xt[tg*4+i][e4*4];
      #pragma unroll
      for (int j = 0; j < 9; j++)
        acc[i][j] += xv.x*w[j].x + xv.y*w[j].y + xv.z*w[j].z + xv.w*w[j].w;
    }
    wp += 288;
  }
  #pragma unroll
  for (int i = 0; i < 4; i++)
    #pragma unroll
    for (int j = 0; j < 9; j++)
      kvb[(size_t)(tok0 + tg*4 + i)*288 + ol + 32*j] = acc[i][j];
}

// ---------------- sparse logits + softmax + a_ups. TWO tokens per wave (32-lane halves).
__global__ __launch_bounds__(256) void k_attn1(const float* __restrict__ kvb,
                                               const float* __restrict__ qb,
                                               const float* __restrict__ tau,
                                               const float* __restrict__ bias9,
                                               float* __restrict__ aups,
                                               float* __restrict__ adown, int zmode) {
  int t = threadIdx.x;
  int half = (t >> 5) & 1, ll = t & 31;
  int tid = blockIdx.x * 8 + (t >> 6) * 2 + half;   // 8 tokens per 256-thr block
  int b = tid / NIN, n = tid % NIN;
  int ms[9]; bool dup[9];
  window9(n, ms, dup);
  const float* kp = kvb + (size_t)tid * 288;
  float k0 = kp[ll], k1 = kp[32 + ll], k2 = kp[64 + ll];
  float et = expf(tau[0]);
  float p[9];
  #pragma unroll
  for (int j = 0; j < 9; j++) {
    const float* qp = qb + (size_t)(b*NOUT + ms[j]) * DIN;
    p[j] = k0 * qp[ll] + k1 * qp[32 + ll] + k2 * qp[64 + ll];
  }
  #pragma unroll
  for (int off = 16; off; off >>= 1)
    #pragma unroll
    for (int j = 0; j < 9; j++) p[j] += __shfl_xor(p[j], off, 32);
  const float* bp = bias9 + (size_t)n*9;
  float lg[9];
  #pragma unroll
  for (int j = 0; j < 9; j++)
    lg[j] = dup[j] ? -1e30f : p[j] * et + bp[j];
  float mx = lg[0];
  #pragma unroll
  for (int j = 1; j < 9; j++) mx = fmaxf(mx, lg[j]);
  float s = 0.f, ex[9];
  #pragma unroll
  for (int j = 0; j < 9; j++) { ex[j] = dup[j] ? 0.f : expf(lg[j] - mx); s += ex[j]; }
  float inv = 1.0f / s;
  if (zmode) {
    float* ap = aups + (size_t)tid*NOUT;
    float* dp = adown + (size_t)tid*NOUT;
    #pragma unroll
    for (int k = 0; k < 25; k++) {
      int e = ll + 32*k;
      if (e < NOUT) {
        float v = 0.f;
        #pragma unroll
        for (int j = 0; j < 9; j++)
          if (!dup[j] && e == ms[j]) v = ex[j] * inv;
        ap[e] = v;
        dp[e] = 0.f;
      }
    }
  } else {
    #pragma unroll
    for (int j = 0; j < 9; j++) {
      if (ll == j && !dup[j])
        aups[(size_t)tid*NOUT + ms[j]] = ex[j] * inv;
    }
  }
}

// ---------------- updates gather + LOCAL colsum + LN + residual (+ a_down last iter)
__global__ __launch_bounds__(192) void k_upd(const float* __restrict__ aups,
                                             const float* __restrict__ kvb,
                                             float* __restrict__ xout,
                                             const float* __restrict__ g,
                                             const float* __restrict__ bb,
                                             float* __restrict__ adown, int wadown) {
  __shared__ float avals[4][64];
  __shared__ float red[4][3][2];
  __shared__ float bc[4][2];
  __shared__ float csv[4];
  int b = blockIdx.z;
  int ro0 = blockIdx.y*2, co0 = blockIdx.x*2;
  int r0 = 2*ro0 - 2; if (r0 < 0) r0 = 0;
  int r1 = 2*ro0 + 5; if (r1 > 55) r1 = 55;
  int c0 = 2*co0 - 2; if (c0 < 0) c0 = 0;
  int c1 = 2*co0 + 5; if (c1 > 55) c1 = 55;
  int nr = r1 - r0 + 1, nc = c1 - c0 + 1, cnt = nr*nc;
  int t = threadIdx.x;
  int m0 = ro0*28 + co0, m1 = m0+1, m2 = m0+28, m3 = m0+29;
  if (t < cnt) {
    int ri = t / nc, ci = t % nc;
    int n = (r0 + ri)*56 + (c0 + ci);
    const float* ap = aups + ((size_t)b*NIN + n)*NOUT;
    avals[0][t] = ap[m0]; avals[1][t] = ap[m1];
    avals[2][t] = ap[m2]; avals[3][t] = ap[m3];
  } else if (t < 64) {
    avals[0][t] = 0.f; avals[1][t] = 0.f; avals[2][t] = 0.f; avals[3][t] = 0.f;
  }
  __syncthreads();
  if (t < 64) {
    float cv0 = avals[0][t], cv1 = avals[1][t], cv2 = avals[2][t], cv3 = avals[3][t];
    #pragma unroll
    for (int off = 32; off; off >>= 1) {
      cv0 += __shfl_xor(cv0, off); cv1 += __shfl_xor(cv1, off);
      cv2 += __shfl_xor(cv2, off); cv3 += __shfl_xor(cv3, off);
    }
    if (t == 0) { csv[0]=cv0; csv[1]=cv1; csv[2]=cv2; csv[3]=cv3; }
  }
  __syncthreads();
  float a0=0.f, a1=0.f, a2=0.f, a3=0.f;
  int i = 0;
  for (int ri = 0; ri < nr; ri++) {
    int nbase = (r0 + ri)*56 + c0;
    for (int ci = 0; ci < nc; ci++, i++) {
      float vv = kvb[((size_t)b*NIN + nbase + ci)*288 + 96 + t];
      a0 += avals[0][i]*vv; a1 += avals[1][i]*vv;
      a2 += avals[2][i]*vv; a3 += avals[3][i]*vv;
    }
  }
  float inv0 = 1.0f/(csv[0]+1e-8f);
  float inv1 = 1.0f/(csv[1]+1e-8f);
  float inv2 = 1.0f/(csv[2]+1e-8f);
  float inv3 = 1.0f/(csv[3]+1e-8f);
  if (wadown && t < cnt) {
    int ri = t / nc, ci = t % nc;
    int n = (r0 + ri)*56 + (c0 + ci);
    float* dp = adown + ((size_t)b*NIN + n)*NOUT;
    dp[m0] = avals[0][t]*inv0; dp[m1] = avals[1][t]*inv1;
    dp[m2] = avals[2][t]*inv2; dp[m3] = avals[3][t]*inv3;
  }
  a0 *= inv0; a1 *= inv1; a2 *= inv2; a3 *= inv3;
  float s0=a0,s1=a1,s2=a2,s3=a3, q0=a0*a0,q1=a1*a1,q2=a2*a2,q3=a3*a3;
  #pragma unroll
  for (int off = 32; off; off >>= 1) {
    s0 += __shfl_xor(s0, off); q0 += __shfl_xor(q0, off);
    s1 += __shfl_xor(s1, off); q1 += __shfl_xor(q1, off);
    s2 += __shfl_xor(s2, off); q2 += __shfl_xor(q2, off);
    s3 += __shfl_xor(s3, off); q3 += __shfl_xor(q3, off);
  }
  int w = t >> 6, l = t & 63;
  if (l == 0) {
    red[0][w][0]=s0; red[0][w][1]=q0;
    red[1][w][0]=s1; red[1][w][1]=q1;
    red[2][w][0]=s2; red[2][w][1]=q2;
    red[3][w][0]=s3; red[3][w][1]=q3;
  }
  __syncthreads();
  if (t < 4) {
    float S = red[t][0][0]+red[t][1][0]+red[t][2][0];
    float Q = red[t][0][1]+red[t][1][1]+red[t][2][1];
    float mu = S * (1.0f/192.0f);
    float var = Q * (1.0f/192.0f) - mu*mu;
    bc[t][0] = mu; bc[t][1] = rsqrtf(var + 1e-5f);
  }
  __syncthreads();
  float gt = g[t], bt = bb[t];
  xout[((size_t)b*NOUT+m0)*DOUT + t] += (a0-bc[0][0])*bc[0][1]*gt + bt;
  xout[((size_t)b*NOUT+m1)*DOUT + t] += (a1-bc[1][0])*bc[1][1]*gt + bt;
  xout[((size_t)b*NOUT+m2)*DOUT + t] += (a2-bc[2][0])*bc[2][1]*gt + bt;
  xout[((size_t)b*NOUT+m3)*DOUT + t] += (a3-bc[3][0])*bc[3][1]*gt + bt;
}

// ---------------- FUSED MLP: GEMM1+GELU -> ht(LDS) -> GEMM2+LN+residual(+dout) -> LN -> q-GEMM.
// 8 tokens/block (784 blocks), 256 thr = 8 groups x 32 lanes; group owns one token.
__global__ __launch_bounds__(256) void k_mlpf(float* __restrict__ xout,
                                              const float* __restrict__ w1_4, const float* __restrict__ b1,
                                              const float* __restrict__ w2_4, const float* __restrict__ b2,
                                              const float* __restrict__ gm, const float* __restrict__ bm,
                                              const float* __restrict__ qw4,
                                              const float* __restrict__ lng, const float* __restrict__ lnb,
                                              float* __restrict__ qb,
                                              float* __restrict__ dout, int last) {
  __shared__ float xt[8][196];
  __shared__ float ht[8][388];
  int tok0 = blockIdx.x * 8;
  int t = threadIdx.x;
  const float4* xp = (const float4*)(xout + (size_t)tok0*DOUT);
  for (int i = t; i < 8*48; i += 256) {
    int tok = i / 48, q = i % 48;
    *(float4*)&xt[tok][q*4] = xp[i];
  }
  __syncthreads();
  int ol = t & 31, tg = t >> 5;   // group tg = token tg
  // GEMM1 (K=192, TN=12) + GELU
  float acc[12];
  #pragma unroll
  for (int j = 0; j < 12; j++) acc[j] = 0.f;
  const float4* wp = (const float4*)w1_4 + ol;
  for (int e4 = 0; e4 < 48; e4++) {
    float4 xv = *(const float4*)&xt[tg][e4*4];
    #pragma unroll
    for (int j = 0; j < 12; j++) {
      float4 w = wp[32*j];
      acc[j] += xv.x*w.x + xv.y*w.y + xv.z*w.z + xv.w*w.w;
    }
    wp += 384;
  }
  #pragma unroll
  for (int j = 0; j < 12; j++) {
    int hh = ol + 32*j;
    float v = acc[j] + b1[hh];
    v = 0.5f*v*(1.0f + erff(v*0.70710678118f));
    ht[tg][hh] = v;
  }
  __syncthreads();
  // GEMM2 (K=384, TN=6) + bias + LN(ln_mlp) + residual
  float o2[6];
  #pragma unroll
  for (int j = 0; j < 6; j++) o2[j] = 0.f;
  const float4* w2p = (const float4*)w2_4 + ol;
  for (int h4 = 0; h4 < 96; h4++) {
    float4 hv = *(const float4*)&ht[tg][h4*4];
    #pragma unroll
    for (int j = 0; j < 6; j++) {
      float4 w = w2p[32*j];
      o2[j] += hv.x*w.x + hv.y*w.y + hv.z*w.z + hv.w*w.w;
    }
    w2p += 192;
  }
  float v[6], s = 0.f, sq = 0.f;
  #pragma unroll
  for (int j = 0; j < 6; j++) {
    v[j] = o2[j] + b2[ol + 32*j];
    s += v[j]; sq += v[j]*v[j];
  }
  #pragma unroll
  for (int off = 16; off; off >>= 1) { s += __shfl_xor(s, off, 32); sq += __shfl_xor(sq, off, 32); }
  float mu = s * (1.f/192.f);
  float var = sq * (1.f/192.f) - mu*mu;
  float rs = rsqrtf(var + 1e-5f);
  float nx6[6], s2 = 0.f, sq2 = 0.f;
  #pragma unroll
  for (int j = 0; j < 6; j++) {
    int o = ol + 32*j;
    float nv = (v[j] - mu)*rs*gm[o] + bm[o];
    size_t gi = (size_t)(tok0 + tg)*DOUT + o;
    float nx = xout[gi] + nv;
    xout[gi] = nx;
    if (last) dout[gi] = nx;
    nx6[j] = nx; s2 += nx; sq2 += nx*nx;
  }
  if (last) return;
  // LN(ln_out) in-register (group owns the whole row via its 6 strided elems)
  #pragma unroll
  for (int off = 16; off; off >>= 1) { s2 += __shfl_xor(s2, off, 32); sq2 += __shfl_xor(sq2, off, 32); }
  float mu2 = s2 * (1.f/192.f);
  float var2 = sq2 * (1.f/192.f) - mu2*mu2;
  float rs2 = rsqrtf(var2 + 1e-5f);
  #pragma unroll
  for (int j = 0; j < 6; j++) {
    int o = ol + 32*j;
    ht[tg][o] = (nx6[j] - mu2)*rs2*lng[o] + lnb[o];   // reuse ht LDS rows [0..192)
  }
  __syncthreads();
  // q-GEMM (K=192, TN=3)
  float qa[3] = {0.f, 0.f, 0.f};
  const float4* qp = (const float4*)qw4 + ol;
  for (int e4 = 0; e4 < 48; e4++) {
    float4 xv = *(const float4*)&ht[tg][e4*4];
    #pragma unroll
    for (int j = 0; j < 3; j++) {
      float4 w = qp[32*j];
      qa[j] += xv.x*w.x + xv.y*w.y + xv.z*w.z + xv.w*w.w;
    }
    qp += 96;
  }
  #pragma unroll
  for (int j = 0; j < 3; j++)
    qb[(size_t)(tok0 + tg)*DIN + ol + 32*j] = qa[j];
}

extern "C" void kernel_launch(void* const* d_in, const int* in_sizes, int n_in,
                              void* d_out, int out_size, void* d_ws, size_t ws_size,
                              hipStream_t stream) {
  (void)in_sizes; (void)n_in; (void)ws_size; (void)out_size;
  const float* x        = (const float*)d_in[0];
  const float* conv_w   = (const float*)d_in[1];
  const float* q_w      = (const float*)d_in[2];
  const float* k_w      = (const float*)d_in[3];
  const float* v_w      = (const float*)d_in[4];
  const float* mlp_w1   = (const float*)d_in[5];
  const float* mlp_b1   = (const float*)d_in[6];
  const float* mlp_w2   = (const float*)d_in[7];
  const float* mlp_b2   = (const float*)d_in[8];
  const float* ln_in_g  = (const float*)d_in[9];
  const float* ln_in_b  = (const float*)d_in[10];
  const float* ln_out_g = (const float*)d_in[11];
  const float* ln_out_b = (const float*)d_in[12];
  const float* ln_attn_g= (const float*)d_in[13];
  const float* ln_attn_b= (const float*)d_in[14];
  const float* ln_mlp_g = (const float*)d_in[15];
  const float* ln_mlp_b = (const float*)d_in[16];
  const float* tau      = (const float*)d_in[17];
  const float* rpb      = (const float*)d_in[18];
  const int*   qidx     = (const int*)d_in[20];

  float* out = (float*)d_out;
  float* aups  = out + 1204224;       // 8*784*192
  float* adown = out + 20873216;      // + 8*3136*784

  float* ws   = (float*)d_ws;
  float* wct  = ws;                   // 165888
  float* wkv4 = wct + 165888;         // 27648
  float* qw4  = wkv4 + 27648;         // 18432
  float* w1_4 = qw4 + 18432;          // 73728
  float* w2_4 = w1_4 + 73728;         // 73728
  float* bias9= w2_4 + 73728;         // 28224
  float* kvb  = bias9 + 28224;        // 25088*288
  float* seed0= kvb + (size_t)TOK_IN*288;     // 4 x 6272*192 (dead after k_lnq)
  float* seed1= seed0 + (size_t)TOK_OUT*DOUT;
  float* seed2= seed1 + (size_t)TOK_OUT*DOUT;
  float* seed3= seed2 + (size_t)TOK_OUT*DOUT;
  float* xo   = seed3 + (size_t)TOK_OUT*DOUT; // 6272*192
  float* qb   = xo + (size_t)TOK_OUT*DOUT;    // 6272*96

  k_tr<<<1515, 256, 0, stream>>>(conv_w, k_w, v_w, q_w, mlp_w1, mlp_w2, rpb, qidx,
                                 wct, wkv4, qw4, w1_4, w2_4, bias9);
  k_conv<<<dim3(28, 8, 8), 224, 0, stream>>>(x, wct, seed0, seed1, seed2, seed3);
  k_lnq<<<TOK_OUT/16, 256, 0, stream>>>(seed0, seed1, seed2, seed3, qw4,
                                        ln_out_g, ln_out_b, xo, qb);
  k_kv<<<TOK_IN/32, 256, 0, stream>>>(x, wkv4, ln_in_g, ln_in_b, kvb);

  for (int it = 0; it < 3; it++) {
    k_attn1<<<TOK_IN/8, 256, 0, stream>>>(kvb, qb, tau, bias9, aups, adown, it == 0);
    k_upd<<<dim3(14, 14, NB), 192, 0, stream>>>(aups, kvb, xo, ln_attn_g, ln_attn_b,
                                                adown, it == 2);
    k_mlpf<<<TOK_OUT/8, 256, 0, stream>>>(xo, w1_4, mlp_b1, w2_4, mlp_b2,
                                          ln_mlp_g, ln_mlp_b,
                                          qw4, ln_out_g, ln_out_b, qb,
                                          out, it == 2);
  }
}

// Round 12
// 660.235 us; speedup vs baseline: 1.2807x; 1.2807x over previous
//
#include <hip/hip_runtime.h>
#include <hip/hip_bf16.h>
#include <math.h>

#define NB 8
#define NIN 3136
#define NOUT 784
#define DIN 96
#define DOUT 192
#define HID 384
#define TOK_IN (NB*NIN)    // 25088
#define TOK_OUT (NB*NOUT)  // 6272

// ---------------- window helper
__device__ __forceinline__ void window9(int n, int* ms, bool* dup) {
  int r = n / 56, c = n % 56;
  int rb = r >> 1, cb = c >> 1;
  #pragma unroll
  for (int j = 0; j < 9; j++) {
    int ro = rb + (j/3) - 1; ro = ro < 0 ? 0 : (ro > 27 ? 27 : ro);
    int co = cb + (j%3) - 1; co = co < 0 ? 0 : (co > 27 ? 27 : co);
    ms[j] = ro*28 + co;
  }
  #pragma unroll
  for (int j = 0; j < 9; j++) {
    bool d = false;
    #pragma unroll
    for (int i = 0; i < j; i++) d = d || (ms[i] == ms[j]);
    dup[j] = d;
  }
}

// ---------------- weight transposes + bias9 table (once per launch)
// wct  : [ch=4][kh][ci4m=6][kw][co][4]
// kw4  : [e4=24][96][4]    (k_w)
// vw4  : [e4=24][192][4]   (v_w)
// qwt4 : [d4=24][192][4]   (q_w in [d][e] orientation, for kt = k @ q_w)
// w1_4 : [e4][384][4]
// w2_4 : [h4][192][4]
// bias9: [n][9]
__global__ void k_tr(const float* __restrict__ cw, const float* __restrict__ kw,
                     const float* __restrict__ vw, const float* __restrict__ qw,
                     const float* __restrict__ w1, const float* __restrict__ w2,
                     const float* __restrict__ rpb, const int* __restrict__ qidx,
                     float* __restrict__ wct, float* __restrict__ kw4, float* __restrict__ vw4,
                     float* __restrict__ qwt4,
                     float* __restrict__ w1_4, float* __restrict__ w2_4,
                     float* __restrict__ bias9) {
  int i = blockIdx.x * 256 + threadIdx.x;
  if (i < 165888) {
    int q = i & 3; int t1 = i >> 2;
    int co = t1 % 192; int t2 = t1 / 192;
    int kwi = t2 % 3; int t3 = t2 / 3;
    int ci4m = t3 % 6; int t4 = t3 / 6;
    int kh = t4 % 3; int ch = t4 / 3;      // ch in [0,4)
    wct[i] = cw[((co*96 + ch*24 + ci4m*4 + q)*3 + kh)*3 + kwi];
  } else if (i < 175104) {                       // kw4
    int j = i - 165888; int q = j & 3; int rest = j >> 2;
    int o = rest % 96; int e4 = rest / 96;
    kw4[j] = kw[o*96 + e4*4 + q];
  } else if (i < 193536) {                       // vw4
    int j = i - 175104; int q = j & 3; int rest = j >> 2;
    int o = rest % 192; int e4 = rest / 192;
    vw4[j] = vw[o*96 + e4*4 + q];
  } else if (i < 211968) {                       // qwt4 [d4][e][4], 4 = d-quad
    int j = i - 193536; int q = j & 3; int rest = j >> 2;
    int e = rest % 192; int d4 = rest / 192;
    qwt4[j] = qw[(d4*4 + q)*192 + e];
  } else if (i < 285696) {                       // w1_4
    int j = i - 211968; int q = j & 3; int rest = j >> 2;
    int hh = rest % 384; int e = (rest / 384)*4 + q;
    w1_4[j] = w1[hh*192 + e];
  } else if (i < 359424) {                       // w2_4
    int j = i - 285696; int q = j & 3; int rest = j >> 2;
    int o = rest % 192; int h = (rest / 192)*4 + q;
    w2_4[j] = w2[o*384 + h];
  } else if (i < 387648) {                       // bias9
    int j = i - 359424;
    int j9 = j % 9; int n = j / 9;
    int ms[9]; bool dup[9];
    window9(n, ms, dup);
    bias9[j] = rpb[qidx[(size_t)n*NOUT + ms[j9]]];
  }
}

// ---------------- strided 3x3 conv seed, 4-way ci-split partial sums.
__global__ __launch_bounds__(224, 4) void k_conv(const float* __restrict__ x,
                                                 const float* __restrict__ wct,
                                                 float* __restrict__ s0, float* __restrict__ s1,
                                                 float* __restrict__ s2, float* __restrict__ s3) {
  __shared__ float xs[3][58][24];   // 16.7 KB
  int ho = blockIdx.x;
  int half = blockIdx.y & 1, ch = blockIdx.y >> 1;   // ch in [0,4)
  int b = blockIdx.z;
  int t = threadIdx.x;
  const float* xb0 = x + (size_t)b*NIN*DIN + ch*24;
  for (int i = t; i < 3*58*6; i += 224) {
    int q = i % 6; int rest = i / 6;
    int col = rest % 58; int kh = rest / 58;
    int h = 2*ho - 1 + kh, c = col - 1;
    float4 v = make_float4(0.f,0.f,0.f,0.f);
    if (h >= 0 && h < 56 && c >= 0 && c < 56)
      v = *(const float4*)(xb0 + ((size_t)h*56 + c)*DIN + q*4);
    *(float4*)&xs[kh][col][q*4] = v;
  }
  __syncthreads();
  int ol = t & 31, tg = t >> 5;       // tg in [0,7): wo = 4tg..4tg+3
  int co = half*96 + ol;
  float acc[4][3];
  #pragma unroll
  for (int i = 0; i < 4; i++) { acc[i][0]=0.f; acc[i][1]=0.f; acc[i][2]=0.f; }
  #pragma unroll
  for (int kh = 0; kh < 3; kh++) {
    const float4* wp = (const float4*)wct + (size_t)(ch*3 + kh)*3456 + co;
    const float* xb = &xs[kh][8*tg][0];
    #pragma unroll
    for (int ci4 = 0; ci4 < 6; ci4++) {
      float4 xr[9];
      #pragma unroll
      for (int c = 0; c < 9; c++) xr[c] = *(const float4*)(xb + c*24);
      #pragma unroll
      for (int kwv = 0; kwv < 3; kwv++) {
        float4 w0 = wp[kwv*192], w1 = wp[kwv*192 + 32], w2 = wp[kwv*192 + 64];
        #pragma unroll
        for (int i = 0; i < 4; i++) {
          float4 xv = xr[2*i + kwv];
          acc[i][0] += xv.x*w0.x + xv.y*w0.y + xv.z*w0.z + xv.w*w0.w;
          acc[i][1] += xv.x*w1.x + xv.y*w1.y + xv.z*w1.z + xv.w*w1.w;
          acc[i][2] += xv.x*w2.x + xv.y*w2.y + xv.z*w2.z + xv.w*w2.w;
        }
      }
      wp += 576; xb += 4;
    }
  }
  float* sp = (ch == 0) ? s0 : (ch == 1) ? s1 : (ch == 2) ? s2 : s3;
  #pragma unroll
  for (int i = 0; i < 4; i++)
    #pragma unroll
    for (int j = 0; j < 3; j++)
      sp[((size_t)b*NOUT + ho*28 + 4*tg + i)*DOUT + co + 32*j] = acc[i][j];
}

// ---------------- seed-sum(4) + LN -> xo, + LN -> xqn. 16 tok/block, 256 thr, no LDS
__global__ __launch_bounds__(256) void k_lnq(const float* __restrict__ s0, const float* __restrict__ s1,
                                             const float* __restrict__ s2, const float* __restrict__ s3,
                                             const float* __restrict__ lng, const float* __restrict__ lnb,
                                             float* __restrict__ xo, float* __restrict__ xqn) {
  int tok0 = blockIdx.x * 16;
  int t = threadIdx.x;
  int tok16 = t >> 4, l16 = t & 15;
  size_t base = (size_t)(tok0 + tok16)*DOUT;
  float v[12], s = 0.f, sq = 0.f;
  #pragma unroll
  for (int j = 0; j < 12; j++) {
    int e = l16 + 16*j;
    float vv = s0[base + e] + s1[base + e] + s2[base + e] + s3[base + e];
    v[j] = vv; s += vv; sq += vv*vv;
  }
  #pragma unroll
  for (int off = 8; off; off >>= 1) { s += __shfl_xor(s, off, 16); sq += __shfl_xor(sq, off, 16); }
  float mu = s * (1.f/192.f);
  float var = sq * (1.f/192.f) - mu*mu;
  float rs = rsqrtf(var + 1e-5f);
  float s2a = 0.f, sq2 = 0.f;
  #pragma unroll
  for (int j = 0; j < 12; j++) {
    int e = l16 + 16*j;
    float y = (v[j]-mu)*rs*lng[e] + lnb[e];
    xo[base + e] = y;
    v[j] = y; s2a += y; sq2 += y*y;
  }
  #pragma unroll
  for (int off = 8; off; off >>= 1) { s2a += __shfl_xor(s2a, off, 16); sq2 += __shfl_xor(sq2, off, 16); }
  float mu2 = s2a * (1.f/192.f);
  float var2 = sq2 * (1.f/192.f) - mu2*mu2;
  float rs2 = rsqrtf(var2 + 1e-5f);
  #pragma unroll
  for (int j = 0; j < 12; j++) {
    int e = l16 + 16*j;
    xqn[base + e] = (v[j]-mu2)*rs2*lng[e] + lnb[e];
  }
}

// ---------------- kv: kt = (LN(x)@k_w^T)@q_w, v = LN(x)@v_w^T. 32 tok/block, 256 thr, TM=4
__global__ __launch_bounds__(256) void k_kv(const float* __restrict__ x,
                                            const float* __restrict__ kw4, const float* __restrict__ vw4,
                                            const float* __restrict__ qwt4,
                                            const float* __restrict__ lng, const float* __restrict__ lnb,
                                            float* __restrict__ kvb) {
  __shared__ float xt[32][100];
  __shared__ float ks[32][100];
  int tok0 = blockIdx.x * 32;
  int t = threadIdx.x;
  const float4* xp = (const float4*)(x + (size_t)tok0*DIN);
  for (int i = t; i < 32*24; i += 256) {
    int tok = i / 24, q = i % 24;
    *(float4*)&xt[tok][q*4] = xp[i];
  }
  __syncthreads();
  int tok8 = t >> 3, l8 = t & 7;
  float vv[12], s = 0.f, sq = 0.f;
  #pragma unroll
  for (int j = 0; j < 12; j++) {
    float v = xt[tok8][l8 + 8*j];
    vv[j] = v; s += v; sq += v*v;
  }
  #pragma unroll
  for (int off = 4; off; off >>= 1) { s += __shfl_xor(s, off, 8); sq += __shfl_xor(sq, off, 8); }
  float mu = s * (1.f/96.f);
  float var = sq * (1.f/96.f) - mu*mu;
  float rs = rsqrtf(var + 1e-5f);
  #pragma unroll
  for (int j = 0; j < 12; j++) {
    int e = l8 + 8*j;
    xt[tok8][e] = (vv[j]-mu)*rs*lng[e] + lnb[e];
  }
  __syncthreads();
  int ol = t & 31, tg = t >> 5;     // 8 groups x 4 tokens
  // k GEMM: TN=3 (96 cols), K=96
  float ak[4][3];
  #pragma unroll
  for (int i = 0; i < 4; i++) { ak[i][0]=0.f; ak[i][1]=0.f; ak[i][2]=0.f; }
  const float4* kp = (const float4*)kw4 + ol;
  for (int e4 = 0; e4 < 24; e4++) {
    float4 w0 = kp[0], w1 = kp[32], w2 = kp[64];
    #pragma unroll
    for (int i = 0; i < 4; i++) {
      float4 xv = *(const float4*)&xt[tg*4+i][e4*4];
      ak[i][0] += xv.x*w0.x + xv.y*w0.y + xv.z*w0.z + xv.w*w0.w;
      ak[i][1] += xv.x*w1.x + xv.y*w1.y + xv.z*w1.z + xv.w*w1.w;
      ak[i][2] += xv.x*w2.x + xv.y*w2.y + xv.z*w2.z + xv.w*w2.w;
    }
    kp += 96;
  }
  #pragma unroll
  for (int i = 0; i < 4; i++)
    #pragma unroll
    for (int j = 0; j < 3; j++)
      ks[tg*4+i][ol + 32*j] = ak[i][j];
  __syncthreads();
  // kt GEMM: kt = k @ q_w, K=96(d), TN=6 (192 cols)
  float akt[4][6];
  #pragma unroll
  for (int i = 0; i < 4; i++)
    #pragma unroll
    for (int j = 0; j < 6; j++) akt[i][j] = 0.f;
  const float4* qp = (const float4*)qwt4 + ol;
  for (int d4 = 0; d4 < 24; d4++) {
    float4 w[6];
    #pragma unroll
    for (int j = 0; j < 6; j++) w[j] = qp[32*j];
    #pragma unroll
    for (int i = 0; i < 4; i++) {
      float4 kv4 = *(const float4*)&ks[tg*4+i][d4*4];
      #pragma unroll
      for (int j = 0; j < 6; j++)
        akt[i][j] += kv4.x*w[j].x + kv4.y*w[j].y + kv4.z*w[j].z + kv4.w*w[j].w;
    }
    qp += 192;
  }
  // v GEMM: K=96, TN=6 (192 cols)
  float av[4][6];
  #pragma unroll
  for (int i = 0; i < 4; i++)
    #pragma unroll
    for (int j = 0; j < 6; j++) av[i][j] = 0.f;
  const float4* vp = (const float4*)vw4 + ol;
  for (int e4 = 0; e4 < 24; e4++) {
    float4 w[6];
    #pragma unroll
    for (int j = 0; j < 6; j++) w[j] = vp[32*j];
    #pragma unroll
    for (int i = 0; i < 4; i++) {
      float4 xv = *(const float4*)&xt[tg*4+i][e4*4];
      #pragma unroll
      for (int j = 0; j < 6; j++)
        av[i][j] += xv.x*w[j].x + xv.y*w[j].y + xv.z*w[j].z + xv.w*w[j].w;
    }
    vp += 192;
  }
  #pragma unroll
  for (int i = 0; i < 4; i++) {
    float* op = kvb + (size_t)(tok0 + tg*4 + i)*384;
    #pragma unroll
    for (int j = 0; j < 6; j++) {
      op[ol + 32*j] = akt[i][j];
      op[192 + ol + 32*j] = av[i][j];
    }
  }
}

// ---------------- sparse logits + softmax + a_ups. TWO tokens per wave (32-lane halves).
// logits via kt . LN(x_out)  (q_w pre-folded into kt)
__global__ __launch_bounds__(256) void k_attn1(const float* __restrict__ kvb,
                                               const float* __restrict__ xqn,
                                               const float* __restrict__ tau,
                                               const float* __restrict__ bias9,
                                               float* __restrict__ aups,
                                               float* __restrict__ adown, int zmode) {
  int t = threadIdx.x;
  int half = (t >> 5) & 1, ll = t & 31;
  int tid = blockIdx.x * 8 + (t >> 6) * 2 + half;   // 8 tokens per 256-thr block
  int b = tid / NIN, n = tid % NIN;
  int ms[9]; bool dup[9];
  window9(n, ms, dup);
  const float* kp = kvb + (size_t)tid * 384;
  float kt[6];
  #pragma unroll
  for (int j6 = 0; j6 < 6; j6++) kt[j6] = kp[ll + 32*j6];
  float et = expf(tau[0]);
  float p[9];
  #pragma unroll
  for (int j = 0; j < 9; j++) {
    const float* qp = xqn + (size_t)(b*NOUT + ms[j]) * DOUT;
    float pv = 0.f;
    #pragma unroll
    for (int j6 = 0; j6 < 6; j6++) pv += kt[j6] * qp[ll + 32*j6];
    p[j] = pv;
  }
  #pragma unroll
  for (int off = 16; off; off >>= 1)
    #pragma unroll
    for (int j = 0; j < 9; j++) p[j] += __shfl_xor(p[j], off, 32);
  const float* bp = bias9 + (size_t)n*9;
  float lg[9];
  #pragma unroll
  for (int j = 0; j < 9; j++)
    lg[j] = dup[j] ? -1e30f : p[j] * et + bp[j];
  float mx = lg[0];
  #pragma unroll
  for (int j = 1; j < 9; j++) mx = fmaxf(mx, lg[j]);
  float s = 0.f, ex[9];
  #pragma unroll
  for (int j = 0; j < 9; j++) { ex[j] = dup[j] ? 0.f : expf(lg[j] - mx); s += ex[j]; }
  float inv = 1.0f / s;
  if (zmode) {
    float* ap = aups + (size_t)tid*NOUT;
    float* dp = adown + (size_t)tid*NOUT;
    #pragma unroll
    for (int k = 0; k < 25; k++) {
      int e = ll + 32*k;
      if (e < NOUT) {
        float v = 0.f;
        #pragma unroll
        for (int j = 0; j < 9; j++)
          if (!dup[j] && e == ms[j]) v = ex[j] * inv;
        ap[e] = v;
        dp[e] = 0.f;
      }
    }
  } else {
    #pragma unroll
    for (int j = 0; j < 9; j++) {
      if (ll == j && !dup[j])
        aups[(size_t)tid*NOUT + ms[j]] = ex[j] * inv;
    }
  }
}

// ---------------- updates gather + LOCAL colsum + LN + residual (+ a_down last iter)
__global__ __launch_bounds__(192) void k_upd(const float* __restrict__ aups,
                                             const float* __restrict__ kvb,
                                             float* __restrict__ xout,
                                             const float* __restrict__ g,
                                             const float* __restrict__ bb,
                                             float* __restrict__ adown, int wadown) {
  __shared__ float avals[4][64];
  __shared__ float red[4][3][2];
  __shared__ float bc[4][2];
  __shared__ float csv[4];
  int b = blockIdx.z;
  int ro0 = blockIdx.y*2, co0 = blockIdx.x*2;
  int r0 = 2*ro0 - 2; if (r0 < 0) r0 = 0;
  int r1 = 2*ro0 + 5; if (r1 > 55) r1 = 55;
  int c0 = 2*co0 - 2; if (c0 < 0) c0 = 0;
  int c1 = 2*co0 + 5; if (c1 > 55) c1 = 55;
  int nr = r1 - r0 + 1, nc = c1 - c0 + 1, cnt = nr*nc;
  int t = threadIdx.x;
  int m0 = ro0*28 + co0, m1 = m0+1, m2 = m0+28, m3 = m0+29;
  if (t < cnt) {
    int ri = t / nc, ci = t % nc;
    int n = (r0 + ri)*56 + (c0 + ci);
    const float* ap = aups + ((size_t)b*NIN + n)*NOUT;
    avals[0][t] = ap[m0]; avals[1][t] = ap[m1];
    avals[2][t] = ap[m2]; avals[3][t] = ap[m3];
  } else if (t < 64) {
    avals[0][t] = 0.f; avals[1][t] = 0.f; avals[2][t] = 0.f; avals[3][t] = 0.f;
  }
  __syncthreads();
  if (t < 64) {
    float cv0 = avals[0][t], cv1 = avals[1][t], cv2 = avals[2][t], cv3 = avals[3][t];
    #pragma unroll
    for (int off = 32; off; off >>= 1) {
      cv0 += __shfl_xor(cv0, off); cv1 += __shfl_xor(cv1, off);
      cv2 += __shfl_xor(cv2, off); cv3 += __shfl_xor(cv3, off);
    }
    if (t == 0) { csv[0]=cv0; csv[1]=cv1; csv[2]=cv2; csv[3]=cv3; }
  }
  __syncthreads();
  float a0=0.f, a1=0.f, a2=0.f, a3=0.f;
  int i = 0;
  for (int ri = 0; ri < nr; ri++) {
    int nbase = (r0 + ri)*56 + c0;
    for (int ci = 0; ci < nc; ci++, i++) {
      float vv = kvb[((size_t)b*NIN + nbase + ci)*384 + 192 + t];
      a0 += avals[0][i]*vv; a1 += avals[1][i]*vv;
      a2 += avals[2][i]*vv; a3 += avals[3][i]*vv;
    }
  }
  float inv0 = 1.0f/(csv[0]+1e-8f);
  float inv1 = 1.0f/(csv[1]+1e-8f);
  float inv2 = 1.0f/(csv[2]+1e-8f);
  float inv3 = 1.0f/(csv[3]+1e-8f);
  if (wadown && t < cnt) {
    int ri = t / nc, ci = t % nc;
    int n = (r0 + ri)*56 + (c0 + ci);
    float* dp = adown + ((size_t)b*NIN + n)*NOUT;
    dp[m0] = avals[0][t]*inv0; dp[m1] = avals[1][t]*inv1;
    dp[m2] = avals[2][t]*inv2; dp[m3] = avals[3][t]*inv3;
  }
  a0 *= inv0; a1 *= inv1; a2 *= inv2; a3 *= inv3;
  float s0=a0,s1=a1,s2=a2,s3=a3, q0=a0*a0,q1=a1*a1,q2=a2*a2,q3=a3*a3;
  #pragma unroll
  for (int off = 32; off; off >>= 1) {
    s0 += __shfl_xor(s0, off); q0 += __shfl_xor(q0, off);
    s1 += __shfl_xor(s1, off); q1 += __shfl_xor(q1, off);
    s2 += __shfl_xor(s2, off); q2 += __shfl_xor(q2, off);
    s3 += __shfl_xor(s3, off); q3 += __shfl_xor(q3, off);
  }
  int w = t >> 6, l = t & 63;
  if (l == 0) {
    red[0][w][0]=s0; red[0][w][1]=q0;
    red[1][w][0]=s1; red[1][w][1]=q1;
    red[2][w][0]=s2; red[2][w][1]=q2;
    red[3][w][0]=s3; red[3][w][1]=q3;
  }
  __syncthreads();
  if (t < 4) {
    float S = red[t][0][0]+red[t][1][0]+red[t][2][0];
    float Q = red[t][0][1]+red[t][1][1]+red[t][2][1];
    float mu = S * (1.0f/192.0f);
    float var = Q * (1.0f/192.0f) - mu*mu;
    bc[t][0] = mu; bc[t][1] = rsqrtf(var + 1e-5f);
  }
  __syncthreads();
  float gt = g[t], bt = bb[t];
  xout[((size_t)b*NOUT+m0)*DOUT + t] += (a0-bc[0][0])*bc[0][1]*gt + bt;
  xout[((size_t)b*NOUT+m1)*DOUT + t] += (a1-bc[1][0])*bc[1][1]*gt + bt;
  xout[((size_t)b*NOUT+m2)*DOUT + t] += (a2-bc[2][0])*bc[2][1]*gt + bt;
  xout[((size_t)b*NOUT+m3)*DOUT + t] += (a3-bc[3][0])*bc[3][1]*gt + bt;
}

// ---------------- MLP GEMM1 + GELU -> ht. 32 tokens x 96 hidden per block, TM=4 TN=3
__global__ __launch_bounds__(256) void k_mlp1(const float* __restrict__ xout,
                                              const float* __restrict__ w1_4, const float* __restrict__ b1,
                                              float* __restrict__ ht) {
  __shared__ float xt[32][196];
  int tok0 = blockIdx.x * 32;
  int h0 = blockIdx.y * 96;
  int t = threadIdx.x;
  const float4* xp = (const float4*)(xout + (size_t)tok0*DOUT);
  for (int i = t; i < 32*48; i += 256) {
    int tok = i / 48, q = i % 48;
    *(float4*)&xt[tok][q*4] = xp[i];
  }
  __syncthreads();
  int ol = t & 31, tg = t >> 5;   // 8 groups x 4 tokens
  float acc[4][3];
  #pragma unroll
  for (int i = 0; i < 4; i++) { acc[i][0]=0.f; acc[i][1]=0.f; acc[i][2]=0.f; }
  const float4* wp = (const float4*)w1_4 + h0 + ol;
  for (int e4 = 0; e4 < 48; e4++) {
    float4 w0 = wp[0], w1v = wp[32], w2v = wp[64];
    #pragma unroll
    for (int i = 0; i < 4; i++) {
      float4 xv = *(const float4*)&xt[tg*4+i][e4*4];
      acc[i][0] += xv.x*w0.x + xv.y*w0.y + xv.z*w0.z + xv.w*w0.w;
      acc[i][1] += xv.x*w1v.x + xv.y*w1v.y + xv.z*w1v.z + xv.w*w1v.w;
      acc[i][2] += xv.x*w2v.x + xv.y*w2v.y + xv.z*w2v.z + xv.w*w2v.w;
    }
    wp += 384;
  }
  #pragma unroll
  for (int j = 0; j < 3; j++) {
    int hh = h0 + ol + 32*j;
    float bv = b1[hh];
    #pragma unroll
    for (int i = 0; i < 4; i++) {
      float v = acc[i][j] + bv;
      v = 0.5f*v*(1.0f + erff(v*0.70710678118f));
      ht[(size_t)(tok0 + tg*4 + i)*HID + hh] = v;
    }
  }
}

// ---------------- MLP GEMM2 + LN + residual (+dout) + LN -> xqn. 16 tok/block, TM=2
__global__ __launch_bounds__(256) void k_mlpq(float* __restrict__ xout,
                                              const float* __restrict__ ht,
                                              const float* __restrict__ w2_4, const float* __restrict__ b2,
                                              const float* __restrict__ g, const float* __restrict__ bb,
                                              const float* __restrict__ lng, const float* __restrict__ lnb,
                                              float* __restrict__ xqn,
                                              float* __restrict__ dout, int last) {
  __shared__ float hs[16][388];
  int tok0 = blockIdx.x * 16;
  int t = threadIdx.x;
  const float4* hp = (const float4*)(ht + (size_t)tok0*HID);
  for (int i = t; i < 16*96; i += 256) {
    int tok = i / 96, q = i % 96;
    *(float4*)&hs[tok][q*4] = hp[i];
  }
  __syncthreads();
  int ol = t & 31, tg = t >> 5;   // 8 groups x 2 tokens
  float acc[2][6];
  #pragma unroll
  for (int i = 0; i < 2; i++)
    #pragma unroll
    for (int j = 0; j < 6; j++) acc[i][j] = 0.f;
  const float4* wp = (const float4*)w2_4 + ol;
  for (int h4 = 0; h4 < 96; h4++) {
    float4 w[6];
    #pragma unroll
    for (int j = 0; j < 6; j++) w[j] = wp[32*j];
    #pragma unroll
    for (int i = 0; i < 2; i++) {
      float4 hv = *(const float4*)&hs[tg*2+i][h4*4];
      #pragma unroll
      for (int j = 0; j < 6; j++)
        acc[i][j] += hv.x*w[j].x + hv.y*w[j].y + hv.z*w[j].z + hv.w*w[j].w;
    }
    wp += 192;
  }
  #pragma unroll
  for (int i = 0; i < 2; i++) {
    int tok = tok0 + tg*2 + i;
    float v[6], s = 0.f, sq = 0.f;
    #pragma unroll
    for (int j = 0; j < 6; j++) {
      v[j] = acc[i][j] + b2[ol + 32*j];
      s += v[j]; sq += v[j]*v[j];
    }
    #pragma unroll
    for (int off = 16; off; off >>= 1) { s += __shfl_xor(s, off, 32); sq += __shfl_xor(sq, off, 32); }
    float mu = s * (1.f/192.f);
    float var = sq * (1.f/192.f) - mu*mu;
    float rs = rsqrtf(var + 1e-5f);
    float nx6[6], s2 = 0.f, sq2 = 0.f;
    #pragma unroll
    for (int j = 0; j < 6; j++) {
      int o = ol + 32*j;
      float nv = (v[j] - mu)*rs*g[o] + bb[o];
      size_t gi = (size_t)tok*DOUT + o;
      float nx = xout[gi] + nv;
      xout[gi] = nx;
      if (last) dout[gi] = nx;
      nx6[j] = nx; s2 += nx; sq2 += nx*nx;
    }
    if (!last) {
      #pragma unroll
      for (int off = 16; off; off >>= 1) { s2 += __shfl_xor(s2, off, 32); sq2 += __shfl_xor(sq2, off, 32); }
      float mu2 = s2 * (1.f/192.f);
      float var2 = sq2 * (1.f/192.f) - mu2*mu2;
      float rs2 = rsqrtf(var2 + 1e-5f);
      #pragma unroll
      for (int j = 0; j < 6; j++) {
        int o = ol + 32*j;
        xqn[(size_t)tok*DOUT + o] = (nx6[j] - mu2)*rs2*lng[o] + lnb[o];
      }
    }
  }
}

extern "C" void kernel_launch(void* const* d_in, const int* in_sizes, int n_in,
                              void* d_out, int out_size, void* d_ws, size_t ws_size,
                              hipStream_t stream) {
  (void)in_sizes; (void)n_in; (void)ws_size; (void)out_size;
  const float* x        = (const float*)d_in[0];
  const float* conv_w   = (const float*)d_in[1];
  const float* q_w      = (const float*)d_in[2];
  const float* k_w      = (const float*)d_in[3];
  const float* v_w      = (const float*)d_in[4];
  const float* mlp_w1   = (const float*)d_in[5];
  const float* mlp_b1   = (const float*)d_in[6];
  const float* mlp_w2   = (const float*)d_in[7];
  const float* mlp_b2   = (const float*)d_in[8];
  const float* ln_in_g  = (const float*)d_in[9];
  const float* ln_in_b  = (const float*)d_in[10];
  const float* ln_out_g = (const float*)d_in[11];
  const float* ln_out_b = (const float*)d_in[12];
  const float* ln_attn_g= (const float*)d_in[13];
  const float* ln_attn_b= (const float*)d_in[14];
  const float* ln_mlp_g = (const float*)d_in[15];
  const float* ln_mlp_b = (const float*)d_in[16];
  const float* tau      = (const float*)d_in[17];
  const float* rpb      = (const float*)d_in[18];
  const int*   qidx     = (const int*)d_in[20];

  float* out = (float*)d_out;
  float* aups  = out + 1204224;       // 8*784*192
  float* adown = out + 20873216;      // + 8*3136*784

  float* ws   = (float*)d_ws;
  float* wct  = ws;                    // 165888
  float* kw4  = wct + 165888;          // 9216
  float* vw4  = kw4 + 9216;            // 18432
  float* qwt4 = vw4 + 18432;           // 18432
  float* w1_4 = qwt4 + 18432;          // 73728
  float* w2_4 = w1_4 + 73728;          // 73728
  float* bias9= w2_4 + 73728;          // 28224
  float* kvb  = bias9 + 28224;         // 25088*384 (kt | v)
  float* seed0= kvb + (size_t)TOK_IN*384;     // 4 x 6272*192 (dead after k_lnq)
  float* seed1= seed0 + (size_t)TOK_OUT*DOUT;
  float* seed2= seed1 + (size_t)TOK_OUT*DOUT;
  float* seed3= seed2 + (size_t)TOK_OUT*DOUT;
  float* xo   = seed3 + (size_t)TOK_OUT*DOUT; // 6272*192
  float* xqn  = xo + (size_t)TOK_OUT*DOUT;    // 6272*192
  float* htb  = seed0;                        // alias: seeds dead once k_lnq ran

  k_tr<<<1515, 256, 0, stream>>>(conv_w, k_w, v_w, q_w, mlp_w1, mlp_w2, rpb, qidx,
                                 wct, kw4, vw4, qwt4, w1_4, w2_4, bias9);
  k_conv<<<dim3(28, 8, 8), 224, 0, stream>>>(x, wct, seed0, seed1, seed2, seed3);
  k_lnq<<<TOK_OUT/16, 256, 0, stream>>>(seed0, seed1, seed2, seed3,
                                        ln_out_g, ln_out_b, xo, xqn);
  k_kv<<<TOK_IN/32, 256, 0, stream>>>(x, kw4, vw4, qwt4, ln_in_g, ln_in_b, kvb);

  for (int it = 0; it < 3; it++) {
    k_attn1<<<TOK_IN/8, 256, 0, stream>>>(kvb, xqn, tau, bias9, aups, adown, it == 0);
    k_upd<<<dim3(14, 14, NB), 192, 0, stream>>>(aups, kvb, xo, ln_attn_g, ln_attn_b,
                                                adown, it == 2);
    k_mlp1<<<dim3(TOK_OUT/32, 4), 256, 0, stream>>>(xo, w1_4, mlp_b1, htb);
    k_mlpq<<<TOK_OUT/16, 256, 0, stream>>>(xo, htb, w2_4, mlp_b2,
                                           ln_mlp_g, ln_mlp_b,
                                           ln_out_g, ln_out_b, xqn,
                                           out, it == 2);
  }
}